// Round 13
// baseline (544.285 us; speedup 1.0000x reference)
//
#include <hip/hip_runtime.h>
#include <hip/hip_bf16.h>

typedef unsigned long long u64;
typedef __bf16 bf16x8 __attribute__((ext_vector_type(8)));
typedef float f32x4 __attribute__((ext_vector_type(4)));
typedef unsigned short ushort8_t __attribute__((ext_vector_type(8)));

#define TOKS 8192
#define DMODEL 2048
#define FD 1024
#define NEXP 7
#define CAP 1170
#define CAPP 1280
#define URT128 134  // 128-row unified tiles: 64 shared + 7*10 routed

#define MFMA16(a, b, c) __builtin_amdgcn_mfma_f32_16x16x32_bf16(a, b, c, 0, 0, 0)

__device__ __forceinline__ unsigned short f2bf(float f) {
  __hip_bfloat16 b = __float2bfloat16(f);
  return __builtin_bit_cast(unsigned short, b);
}
__device__ __forceinline__ float bf2f(unsigned short u) {
  __hip_bfloat16 b = __builtin_bit_cast(__hip_bfloat16, u);
  return __bfloat162float(b);
}
__device__ __forceinline__ void gload_lds16(const void* g, void* l) {
  __builtin_amdgcn_global_load_lds(
      (const __attribute__((address_space(1))) void*)g,
      (__attribute__((address_space(3))) void*)l, 16, 0, 0);
}

// ---------------- fused x fp32->bf16 convert + gating (1 block = 1 token) ----------------
__global__ __launch_bounds__(256) void k_conv_gate(
    const float* __restrict__ x, const float* __restrict__ gw,
    const float* __restrict__ bias, unsigned short* __restrict__ xb,
    u64* __restrict__ keys, unsigned* __restrict__ cnt) {
  const int t = blockIdx.x;
  const int tid = threadIdx.x;
  const int lane = tid & 63, wv = tid >> 6;
  if (tid == 0) cnt[t] = 0;  // zero inverse-map counter
  const float* xr = x + (long)t * DMODEL;
  const int i0 = tid * 8;
  float4 v0 = *(const float4*)&xr[i0];
  float4 v1 = *(const float4*)&xr[i0 + 4];
  float xv[8] = {v0.x, v0.y, v0.z, v0.w, v1.x, v1.y, v1.z, v1.w};
  ushort8_t o;
#pragma unroll
  for (int j = 0; j < 8; ++j) o[j] = f2bf(xv[j]);
  *(ushort8_t*)&xb[(long)t * DMODEL + i0] = o;
  double acc[NEXP];
#pragma unroll
  for (int e = 0; e < NEXP; ++e) acc[e] = 0.0;
#pragma unroll
  for (int j = 0; j < 8; ++j) {
    const float* g = gw + (long)(i0 + j) * NEXP;
    double xd = (double)xv[j];
#pragma unroll
    for (int e = 0; e < NEXP; ++e) acc[e] += xd * (double)g[e];
  }
#pragma unroll
  for (int e = 0; e < NEXP; ++e)
    for (int off = 32; off > 0; off >>= 1)
      acc[e] += __shfl_down(acc[e], off, 64);
  __shared__ double red[4][NEXP];
  if (lane == 0)
#pragma unroll
    for (int e = 0; e < NEXP; ++e) red[wv][e] = acc[e];
  __syncthreads();
  if (tid == 0) {
    float aff[NEXP];
#pragma unroll
    for (int e = 0; e < NEXP; ++e) {
      double lg = red[0][e] + red[1][e] + red[2][e] + red[3][e] + (double)bias[e];
      aff[e] = (float)(1.0 / (1.0 + exp(-lg)));
    }
    int i1 = 0;
    for (int e = 1; e < NEXP; ++e) if (aff[e] > aff[i1]) i1 = e;
    int i2 = -1;
    for (int e = 0; e < NEXP; ++e) {
      if (e == i1) continue;
      if (i2 < 0 || aff[e] > aff[i2]) i2 = e;
    }
#pragma unroll
    for (int e = 0; e < NEXP; ++e) {
      u64 key = (u64)(0xFFFFFFFFu - (unsigned)t);
      if (e == i1 || e == i2) key |= ((u64)__float_as_uint(aff[e])) << 32;
      keys[(long)e * TOKS + t] = key;
    }
  }
}

// ---------------- vectorized transpose fp32 [R][C] -> bf16 [C][R], 64x64 tiles ----------------
template <bool PERM>
__global__ __launch_bounds__(256) void k_tr64(
    const float* __restrict__ in0, const float* __restrict__ inr,
    unsigned short* __restrict__ out, int R, int C) {
  __shared__ float t[64][65];
  const int z = blockIdx.z;
  const float* in = (z == 0) ? in0 : (inr + (long)(z - 1) * R * C);
  unsigned short* o = out + (long)z * R * C;
  const int c0 = blockIdx.x * 64;
  const int r0 = blockIdx.y * 64;
  const int tid = threadIdx.x;
  const int rr = tid >> 4;
  const int cc4 = (tid & 15) * 4;
#pragma unroll
  for (int i = 0; i < 4; ++i) {
    int r = rr + 16 * i;
    float4 v = *(const float4*)&in[(long)(r0 + r) * C + c0 + cc4];
    t[r][cc4 + 0] = v.x;
    t[r][cc4 + 1] = v.y;
    t[r][cc4 + 2] = v.z;
    t[r][cc4 + 3] = v.w;
  }
  __syncthreads();
#pragma unroll
  for (int h = 0; h < 2; ++h) {
    int c = tid + h * 256;
    int oc = c >> 3;
    int j = c & 7;
    ushort8_t v8;
#pragma unroll
    for (int q = 0; q < 8; ++q) v8[q] = f2bf(t[j * 8 + q][oc]);
    int gc = c0 + oc;
    long orow = PERM ? (long)(((gc & 1023) >> 4) * 32 + ((gc >> 10) << 4) + (gc & 15))
                     : (long)gc;
    *(ushort8_t*)&o[orow * R + r0 + j * 8] = v8;
  }
}

// ---------------- per-expert radix-select of top-CAP keys + inverse map ----------------
__global__ __launch_bounds__(1024) void k_select(
    const u64* __restrict__ keys, int* __restrict__ sel,
    float* __restrict__ selw, unsigned* __restrict__ cnt,
    int* __restrict__ inv) {
  __shared__ unsigned hist[256];
  __shared__ u64 s_prefix;
  __shared__ unsigned s_k;
  __shared__ unsigned s_cnt;
  const int e = blockIdx.x;
  const u64* kk = keys + (long)e * TOKS;
  const int tid = threadIdx.x;
  if (tid == 0) { s_prefix = 0; s_k = CAP; s_cnt = 0; }
  __syncthreads();
  for (int shift = 56; shift >= 0; shift -= 8) {
    if (tid < 256) hist[tid] = 0;
    __syncthreads();
    u64 pref = s_prefix;
    for (int i = tid; i < TOKS; i += 1024) {
      u64 key = kk[i];
      bool match = (shift == 56) || ((key >> (shift + 8)) == pref);
      if (match) atomicAdd(&hist[(unsigned)(key >> shift) & 255u], 1u);
    }
    __syncthreads();
    if (tid == 0) {
      unsigned k = s_k, cum = 0;
      for (int b = 255; b >= 0; --b) {
        unsigned c = hist[b];
        if (cum + c >= k) {
          s_prefix = (s_prefix << 8) | (unsigned)b;
          s_k = k - cum;
          break;
        }
        cum += c;
      }
    }
    __syncthreads();
  }
  const u64 T = s_prefix;  // exact CAP-th largest key
  for (int i = tid; i < TOKS; i += 1024) {
    u64 key = kk[i];
    if (key >= T) {
      unsigned p = atomicAdd(&s_cnt, 1u);
      int tok = (int)(0xFFFFFFFFu - (unsigned)(key & 0xFFFFFFFFull));
      unsigned vb = (unsigned)(key >> 32);
      sel[e * CAPP + p] = tok;
      selw[e * CAPP + p] = vb ? __uint_as_float(vb) : 0.0f;
      if (vb) {
        unsigned pos = atomicAdd(&cnt[tok], 1u);
        inv[tok * 2 + pos] = e * CAPP + (int)p;
      }
    }
  }
  for (int i = CAP + tid; i < CAPP; i += 1024) {
    sel[e * CAPP + i] = 0;
    selw[e * CAPP + i] = 0.0f;
  }
}

// ---------------- combine: out[tok] = f32(o_all[tok]) + sum of routed o_all rows ----------------
__global__ __launch_bounds__(256) void k_combine(
    float* __restrict__ out, const unsigned short* __restrict__ o_all,
    const int* __restrict__ inv, const unsigned* __restrict__ cnt) {
  const int tok = blockIdx.x;
  const unsigned c = cnt[tok];
  int i0 = -1, i1 = -1;
  if (c > 0) {
    i0 = inv[tok * 2];
    if (c > 1) {
      i1 = inv[tok * 2 + 1];
      if (i1 < i0) { int t = i0; i0 = i1; i1 = t; }  // canonical order
    }
  }
  const int col = threadIdx.x * 8;
  ushort8_t s = *(const ushort8_t*)&o_all[(long)tok * DMODEL + col];
  float v[8];
#pragma unroll
  for (int q = 0; q < 8; ++q) v[q] = bf2f(s[q]);
  if (i0 >= 0) {
    ushort8_t r = *(const ushort8_t*)&o_all[(long)(TOKS + i0) * DMODEL + col];
#pragma unroll
    for (int q = 0; q < 8; ++q) v[q] += bf2f(r[q]);
  }
  if (i1 >= 0) {
    ushort8_t r = *(const ushort8_t*)&o_all[(long)(TOKS + i1) * DMODEL + col];
#pragma unroll
    for (int q = 0; q < 8; ++q) v[q] += bf2f(r[q]);
  }
  float* op = out + (long)tok * DMODEL + col;
  *(float4*)op = make_float4(v[0], v[1], v[2], v[3]);
  *(float4*)(op + 4) = make_float4(v[4], v[5], v[6], v[7]);
}

// ---------------- fused 128x128 2-phase GEMM, capacity-tuned to EXACTLY 3 blocks/CU ----------------
// Dynamic LDS padded to 53 KB: floor(160/53) = 3 -> 2144 tiles / 768 slots = 2.79 -> ceil 3
// generations at 93% quantization efficiency (vs the 70% wall of every prior config).
// WHICH=1: xb[gathered] @ w1t[zw]^T (K=2048) -> SwiGLU -> a_all bf16 [17152][1024]
// WHICH=2: a_all @ w2t[zw]^T (K=1024) -> weighted bf16 o_all [17152][2048]
// Grid (16, 134) with supertile locality swizzle (R7-proven).
template <int WHICH>
__global__ __launch_bounds__(256, 3) void k_ffn(
    const unsigned short* __restrict__ Abase,
    const unsigned short* __restrict__ Wbase,
    unsigned short* __restrict__ obuf, const int* __restrict__ sel,
    const float* __restrict__ selw) {
  constexpr int K = (WHICH == 1) ? DMODEL : FD;
  constexpr int N = 2048;
  constexpr int nk = K >> 5;
  extern __shared__ unsigned short lds[];  // 2 bufs x 8192 shorts used; padded to 53KB
  const int tid = threadIdx.x;
  const int w = tid >> 6;
  const int lane = tid & 63;

  // locality swizzle over grid (16,134): per-XCD 268-tile run, supertiles 8x16 col-outer
  int lin = blockIdx.x + ((int)blockIdx.y << 4);
  int gt = (lin & 7) * 268 + (lin >> 3);
  int ct, rt, su;
  if (gt < 2048) { su = gt >> 7; int rr = gt & 127; ct = rr >> 3; rt = rr & 7; }
  else           { su = 16;      int rr = gt - 2048; ct = rr / 6; rt = rr % 6; }
  const int by_u = su * 8 + rt;  // 0..133
  const int bx = ct;             // 0..15

  int e, zw, m0l;
  if (by_u < 64) { e = -1; zw = 0; m0l = by_u << 7; }
  else { int q = by_u - 64; e = q / 10; zw = e + 1; m0l = (q % 10) << 7; }
  const long crow0_u = (e < 0) ? (long)m0l : (8192 + (long)e * CAPP + m0l);
  const long n0 = (long)bx * 128;
  const unsigned short* Bm = Wbase + (long)zw * N * K;

  // staging: 4 chunks/thread (2 A + 2 B), pre-swizzled source col
  const int r_ = (w << 4) + (lane >> 2);
  const int p_ = lane & 3;
  const unsigned short* aSrc[2];
  const unsigned short* bSrc[2];
#pragma unroll
  for (int c = 0; c < 2; ++c) {
    int rsg = c * 64 + r_;
    int q = p_ ^ ((rsg >> 1) & 3);
    long arow;
    if (WHICH == 1)
      arow = (e < 0) ? (long)(m0l + rsg) : (long)sel[e * CAPP + m0l + rsg];
    else
      arow = crow0_u + rsg;
    aSrc[c] = Abase + arow * (long)K + q * 8;
    bSrc[c] = Bm + (n0 + rsg) * (long)K + q * 8;
  }
  const int dst0 = tid * 8;

  auto STAGE = [&](int buf, int kt) {
    unsigned short* bufp = lds + buf * 8192;
    const long ko = (long)kt * 32;
#pragma unroll
    for (int c = 0; c < 2; ++c) {
      gload_lds16(aSrc[c] + ko, bufp + c * 2048 + dst0);
      gload_lds16(bSrc[c] + ko, bufp + 4096 + c * 2048 + dst0);
    }
  };

  const int wr = w >> 1, wc = w & 1;
  const int lr = lane & 15, kq = lane >> 4;
  const int slot = (kq ^ ((lr >> 1) & 3)) * 8;
  const int aRow = wr * 64 + lr;
  const int bRow = wc * 64 + lr;

  STAGE(0, 0);
  asm volatile("s_waitcnt vmcnt(0)" ::: "memory");
  __builtin_amdgcn_sched_barrier(0);
  __builtin_amdgcn_s_barrier();
  __builtin_amdgcn_sched_barrier(0);

  f32x4 acc[4][4] = {};
  int cur = 0;

#pragma unroll 1
  for (int kt = 0; kt < nk; ++kt) {
    if (kt + 1 < nk) STAGE(cur ^ 1, kt + 1);
    const unsigned short* aSeg = lds + cur * 8192;
    const unsigned short* bSeg = aSeg + 4096;
    bf16x8 af[4], bf[4];
#pragma unroll
    for (int m = 0; m < 4; ++m)
      af[m] = *(const bf16x8*)&aSeg[(aRow + m * 16) * 32 + slot];
#pragma unroll
    for (int n = 0; n < 4; ++n)
      bf[n] = *(const bf16x8*)&bSeg[(bRow + n * 16) * 32 + slot];
    asm volatile("s_waitcnt lgkmcnt(0)" ::: "memory");
    __builtin_amdgcn_sched_barrier(0);
    __builtin_amdgcn_s_setprio(1);
#pragma unroll
    for (int m = 0; m < 4; ++m)
#pragma unroll
      for (int n = 0; n < 4; ++n)
        acc[m][n] = MFMA16(af[m], bf[n], acc[m][n]);
    __builtin_amdgcn_s_setprio(0);
    asm volatile("s_waitcnt vmcnt(0)" ::: "memory");
    __builtin_amdgcn_sched_barrier(0);
    __builtin_amdgcn_s_barrier();
    __builtin_amdgcn_sched_barrier(0);
    cur ^= 1;
  }

  // ---- epilogue ----
  const int r0q = (lane >> 4) * 4;
  const int cc = lane & 15;

  if (WHICH == 1) {  // SwiGLU -> a_all bf16 [17152][FD]
    const long gcol0 = (n0 >> 1) + wc * 32;
#pragma unroll
    for (int m = 0; m < 4; ++m)
#pragma unroll
      for (int rj = 0; rj < 4; ++rj) {
        long row = crow0_u + wr * 64 + m * 16 + r0q + rj;
#pragma unroll
        for (int q2 = 0; q2 < 2; ++q2) {
          float x1v = acc[m][2 * q2][rj];
          float x2v = acc[m][2 * q2 + 1][rj];
          float s = x2v / (1.0f + __expf(-x2v));
          obuf[row * FD + gcol0 + q2 * 16 + cc] = f2bf(x1v * s);
        }
      }
  } else {  // unified weighted bf16 -> o_all [17152][2048]
    const long ccol0 = n0 + wc * 64;
#pragma unroll
    for (int m = 0; m < 4; ++m)
#pragma unroll
      for (int rj = 0; rj < 4; ++rj) {
        int lrow = m0l + wr * 64 + m * 16 + r0q + rj;
        float wgt = (e < 0) ? 1.0f : selw[e * CAPP + lrow];
        long row = crow0_u + wr * 64 + m * 16 + r0q + rj;
#pragma unroll
        for (int n = 0; n < 4; ++n)
          obuf[row * DMODEL + ccol0 + n * 16 + cc] = f2bf(acc[m][n][rj] * wgt);
      }
  }
}

extern "C" void kernel_launch(void* const* d_in, const int* in_sizes, int n_in,
                              void* d_out, int out_size, void* d_ws,
                              size_t ws_size, hipStream_t stream) {
  (void)in_sizes; (void)n_in; (void)out_size; (void)ws_size;
  const float* x = (const float*)d_in[0];
  const float* gw = (const float*)d_in[1];
  const float* eb = (const float*)d_in[2];
  const float* sw1 = (const float*)d_in[3];
  const float* sw2 = (const float*)d_in[4];
  const float* rw1 = (const float*)d_in[5];
  const float* rw2 = (const float*)d_in[6];
  float* out = (float*)d_out;

  char* ws = (char*)d_ws;
  size_t off = 0;
  auto alloc = [&](size_t bytes) {
    size_t o = off;
    off += (bytes + 255) & ~(size_t)255;
    return o;
  };
  unsigned short* xb    = (unsigned short*)(ws + alloc((size_t)TOKS * DMODEL * 2));
  unsigned short* w1t   = (unsigned short*)(ws + alloc((size_t)8 * DMODEL * (2 * FD) * 2));
  unsigned short* w2t   = (unsigned short*)(ws + alloc((size_t)8 * DMODEL * FD * 2));
  unsigned short* a_all = (unsigned short*)(ws + alloc((size_t)(TOKS + NEXP * CAPP) * FD * 2));
  unsigned short* o_all = (unsigned short*)(ws + alloc((size_t)(TOKS + NEXP * CAPP) * DMODEL * 2));
  u64* keys = (u64*)(ws + alloc((size_t)NEXP * TOKS * 8));
  int* sel  = (int*)(ws + alloc((size_t)NEXP * CAPP * 4));
  float* selw = (float*)(ws + alloc((size_t)NEXP * CAPP * 4));
  unsigned* cnt = (unsigned*)(ws + alloc((size_t)TOKS * 4));
  int* inv = (int*)(ws + alloc((size_t)TOKS * 2 * 4));

  // Dynamic LDS padded to force EXACTLY 3 blocks/CU: 160KB/3 = 54.6KB max; use 53KB.
  // (Kernel uses only 32KB; the pad is pure occupancy control.)
  const size_t LDS3 = 54272;

  // 1. fused convert + gating (also zeroes cnt)
  k_conv_gate<<<TOKS, 256, 0, stream>>>(x, gw, eb, xb, keys, cnt);
  // 2./3. vectorized weight transposes (w1 with x1/x2 16-block interleave)
  k_tr64<true><<<dim3(32, 32, 8), 256, 0, stream>>>(sw1, rw1, w1t, DMODEL, 2 * FD);
  k_tr64<false><<<dim3(32, 16, 8), 256, 0, stream>>>(sw2, rw2, w2t, FD, DMODEL);
  // 4. per-expert selection + inverse map
  k_select<<<NEXP, 1024, 0, stream>>>(keys, sel, selw, cnt, inv);
  // 5. GEMM1 (128^2 2-phase, c=3 capacity-tuned) + SwiGLU -> a_all
  k_ffn<1><<<dim3(16, URT128), 256, LDS3, stream>>>(xb, w1t, a_all, sel, nullptr);
  // 6. GEMM2 (same structure) -> o_all bf16 (shared w=1, routed w=selw)
  k_ffn<2><<<dim3(16, URT128), 256, LDS3, stream>>>(a_all, w2t, o_all, nullptr, selw);
  // 7. combine -> out fp32 (full overwrite)
  k_combine<<<TOKS, 256, 0, stream>>>(out, o_all, inv, cnt);
}

// Round 14
// 500.870 us; speedup vs baseline: 1.0867x; 1.0867x over previous
//
#include <hip/hip_runtime.h>
#include <hip/hip_bf16.h>

typedef unsigned long long u64;
typedef __bf16 bf16x8 __attribute__((ext_vector_type(8)));
typedef float f32x4 __attribute__((ext_vector_type(4)));
typedef unsigned short ushort8_t __attribute__((ext_vector_type(8)));

#define TOKS 8192
#define DMODEL 2048
#define FD 1024
#define NEXP 7
#define CAP 1170
#define CAPP 1280
#define URT128 134  // 128-row unified tiles: 64 shared + 7*10 routed

#define MFMA16(a, b, c) __builtin_amdgcn_mfma_f32_16x16x32_bf16(a, b, c, 0, 0, 0)

__device__ __forceinline__ unsigned short f2bf(float f) {
  __hip_bfloat16 b = __float2bfloat16(f);
  return __builtin_bit_cast(unsigned short, b);
}
__device__ __forceinline__ float bf2f(unsigned short u) {
  __hip_bfloat16 b = __builtin_bit_cast(__hip_bfloat16, u);
  return __bfloat162float(b);
}
__device__ __forceinline__ void gload_lds16(const void* g, void* l) {
  __builtin_amdgcn_global_load_lds(
      (const __attribute__((address_space(1))) void*)g,
      (__attribute__((address_space(3))) void*)l, 16, 0, 0);
}

// ---------------- fused x fp32->bf16 convert + gating (1 block = 1 token) ----------------
__global__ __launch_bounds__(256) void k_conv_gate(
    const float* __restrict__ x, const float* __restrict__ gw,
    const float* __restrict__ bias, unsigned short* __restrict__ xb,
    u64* __restrict__ keys, unsigned* __restrict__ cnt) {
  const int t = blockIdx.x;
  const int tid = threadIdx.x;
  const int lane = tid & 63, wv = tid >> 6;
  if (tid == 0) cnt[t] = 0;  // zero inverse-map counter
  const float* xr = x + (long)t * DMODEL;
  const int i0 = tid * 8;
  float4 v0 = *(const float4*)&xr[i0];
  float4 v1 = *(const float4*)&xr[i0 + 4];
  float xv[8] = {v0.x, v0.y, v0.z, v0.w, v1.x, v1.y, v1.z, v1.w};
  ushort8_t o;
#pragma unroll
  for (int j = 0; j < 8; ++j) o[j] = f2bf(xv[j]);
  *(ushort8_t*)&xb[(long)t * DMODEL + i0] = o;
  double acc[NEXP];
#pragma unroll
  for (int e = 0; e < NEXP; ++e) acc[e] = 0.0;
#pragma unroll
  for (int j = 0; j < 8; ++j) {
    const float* g = gw + (long)(i0 + j) * NEXP;
    double xd = (double)xv[j];
#pragma unroll
    for (int e = 0; e < NEXP; ++e) acc[e] += xd * (double)g[e];
  }
#pragma unroll
  for (int e = 0; e < NEXP; ++e)
    for (int off = 32; off > 0; off >>= 1)
      acc[e] += __shfl_down(acc[e], off, 64);
  __shared__ double red[4][NEXP];
  if (lane == 0)
#pragma unroll
    for (int e = 0; e < NEXP; ++e) red[wv][e] = acc[e];
  __syncthreads();
  if (tid == 0) {
    float aff[NEXP];
#pragma unroll
    for (int e = 0; e < NEXP; ++e) {
      double lg = red[0][e] + red[1][e] + red[2][e] + red[3][e] + (double)bias[e];
      aff[e] = (float)(1.0 / (1.0 + exp(-lg)));
    }
    int i1 = 0;
    for (int e = 1; e < NEXP; ++e) if (aff[e] > aff[i1]) i1 = e;
    int i2 = -1;
    for (int e = 0; e < NEXP; ++e) {
      if (e == i1) continue;
      if (i2 < 0 || aff[e] > aff[i2]) i2 = e;
    }
#pragma unroll
    for (int e = 0; e < NEXP; ++e) {
      u64 key = (u64)(0xFFFFFFFFu - (unsigned)t);
      if (e == i1 || e == i2) key |= ((u64)__float_as_uint(aff[e])) << 32;
      keys[(long)e * TOKS + t] = key;
    }
  }
}

// ---------------- vectorized transpose fp32 [R][C] -> bf16 [C][R], 64x64 tiles ----------------
template <bool PERM>
__global__ __launch_bounds__(256) void k_tr64(
    const float* __restrict__ in0, const float* __restrict__ inr,
    unsigned short* __restrict__ out, int R, int C) {
  __shared__ float t[64][65];
  const int z = blockIdx.z;
  const float* in = (z == 0) ? in0 : (inr + (long)(z - 1) * R * C);
  unsigned short* o = out + (long)z * R * C;
  const int c0 = blockIdx.x * 64;
  const int r0 = blockIdx.y * 64;
  const int tid = threadIdx.x;
  const int rr = tid >> 4;
  const int cc4 = (tid & 15) * 4;
#pragma unroll
  for (int i = 0; i < 4; ++i) {
    int r = rr + 16 * i;
    float4 v = *(const float4*)&in[(long)(r0 + r) * C + c0 + cc4];
    t[r][cc4 + 0] = v.x;
    t[r][cc4 + 1] = v.y;
    t[r][cc4 + 2] = v.z;
    t[r][cc4 + 3] = v.w;
  }
  __syncthreads();
#pragma unroll
  for (int h = 0; h < 2; ++h) {
    int c = tid + h * 256;
    int oc = c >> 3;
    int j = c & 7;
    ushort8_t v8;
#pragma unroll
    for (int q = 0; q < 8; ++q) v8[q] = f2bf(t[j * 8 + q][oc]);
    int gc = c0 + oc;
    long orow = PERM ? (long)(((gc & 1023) >> 4) * 32 + ((gc >> 10) << 4) + (gc & 15))
                     : (long)gc;
    *(ushort8_t*)&o[orow * R + r0 + j * 8] = v8;
  }
}

// ---------------- per-expert radix-select of top-CAP keys + inverse map ----------------
__global__ __launch_bounds__(1024) void k_select(
    const u64* __restrict__ keys, int* __restrict__ sel,
    float* __restrict__ selw, unsigned* __restrict__ cnt,
    int* __restrict__ inv) {
  __shared__ unsigned hist[256];
  __shared__ u64 s_prefix;
  __shared__ unsigned s_k;
  __shared__ unsigned s_cnt;
  const int e = blockIdx.x;
  const u64* kk = keys + (long)e * TOKS;
  const int tid = threadIdx.x;
  if (tid == 0) { s_prefix = 0; s_k = CAP; s_cnt = 0; }
  __syncthreads();
  for (int shift = 56; shift >= 0; shift -= 8) {
    if (tid < 256) hist[tid] = 0;
    __syncthreads();
    u64 pref = s_prefix;
    for (int i = tid; i < TOKS; i += 1024) {
      u64 key = kk[i];
      bool match = (shift == 56) || ((key >> (shift + 8)) == pref);
      if (match) atomicAdd(&hist[(unsigned)(key >> shift) & 255u], 1u);
    }
    __syncthreads();
    if (tid == 0) {
      unsigned k = s_k, cum = 0;
      for (int b = 255; b >= 0; --b) {
        unsigned c = hist[b];
        if (cum + c >= k) {
          s_prefix = (s_prefix << 8) | (unsigned)b;
          s_k = k - cum;
          break;
        }
        cum += c;
      }
    }
    __syncthreads();
  }
  const u64 T = s_prefix;  // exact CAP-th largest key
  for (int i = tid; i < TOKS; i += 1024) {
    u64 key = kk[i];
    if (key >= T) {
      unsigned p = atomicAdd(&s_cnt, 1u);
      int tok = (int)(0xFFFFFFFFu - (unsigned)(key & 0xFFFFFFFFull));
      unsigned vb = (unsigned)(key >> 32);
      sel[e * CAPP + p] = tok;
      selw[e * CAPP + p] = vb ? __uint_as_float(vb) : 0.0f;
      if (vb) {
        unsigned pos = atomicAdd(&cnt[tok], 1u);
        inv[tok * 2 + pos] = e * CAPP + (int)p;
      }
    }
  }
  for (int i = CAP + tid; i < CAPP; i += 1024) {
    sel[e * CAPP + i] = 0;
    selw[e * CAPP + i] = 0.0f;
  }
}

// ---------------- combine: out[tok] = f32(o_all[tok]) + sum of routed o_all rows ----------------
__global__ __launch_bounds__(256) void k_combine(
    float* __restrict__ out, const unsigned short* __restrict__ o_all,
    const int* __restrict__ inv, const unsigned* __restrict__ cnt) {
  const int tok = blockIdx.x;
  const unsigned c = cnt[tok];
  int i0 = -1, i1 = -1;
  if (c > 0) {
    i0 = inv[tok * 2];
    if (c > 1) {
      i1 = inv[tok * 2 + 1];
      if (i1 < i0) { int t = i0; i0 = i1; i1 = t; }  // canonical order
    }
  }
  const int col = threadIdx.x * 8;
  ushort8_t s = *(const ushort8_t*)&o_all[(long)tok * DMODEL + col];
  float v[8];
#pragma unroll
  for (int q = 0; q < 8; ++q) v[q] = bf2f(s[q]);
  if (i0 >= 0) {
    ushort8_t r = *(const ushort8_t*)&o_all[(long)(TOKS + i0) * DMODEL + col];
#pragma unroll
    for (int q = 0; q < 8; ++q) v[q] += bf2f(r[q]);
  }
  if (i1 >= 0) {
    ushort8_t r = *(const ushort8_t*)&o_all[(long)(TOKS + i1) * DMODEL + col];
#pragma unroll
    for (int q = 0; q < 8; ++q) v[q] += bf2f(r[q]);
  }
  float* op = out + (long)tok * DMODEL + col;
  *(float4*)op = make_float4(v[0], v[1], v[2], v[3]);
  *(float4*)(op + 4) = make_float4(v[4], v[5], v[6], v[7]);
}

// ---------------- fused 128x128 GEMM, 2 K-steps per barrier (4x16KB buffer rotation) ----------------
// Per iteration: stage steps 2i+2,2i+3 (8 gload_lds, latencies overlap) -> compute step 2i
// (ds_read, lgkm, 64 MFMA) -> compute step 2i+1 -> vmcnt(0) -> ONE barrier. Halves the
// number of latency-bound barrier round trips vs R7/R10 (64->32 for K=2048, 32->16 for K=1024).
// Hazards: buffer staged at iter i is read at iter i+1 (after barrier); buffer restaged at
// iter i was computed at iter i-1 (reads retired by lgkmcnt(0) before that iter's barrier).
// WHICH=1: xb[gathered] @ w1t[zw]^T (K=2048) -> SwiGLU -> a_all bf16 [17152][1024]
// WHICH=2: a_all @ w2t[zw]^T (K=1024) -> weighted bf16 o_all [17152][2048]
// Grid (16, 134) with R7-proven supertile locality swizzle. Dynamic LDS 64 KB -> 2 blk/CU.
template <int WHICH>
__global__ __launch_bounds__(256) void k_ffn(
    const unsigned short* __restrict__ Abase,
    const unsigned short* __restrict__ Wbase,
    unsigned short* __restrict__ obuf, const int* __restrict__ sel,
    const float* __restrict__ selw) {
  constexpr int K = (WHICH == 1) ? DMODEL : FD;
  constexpr int N = 2048;
  constexpr int nk = K >> 5;    // 32B-col K-steps
  constexpr int nk2 = nk >> 1;  // iterations (2 steps each)
  extern __shared__ unsigned short lds[];  // 4 bufs x 8192 shorts = 64 KB
  const int tid = threadIdx.x;
  const int w = tid >> 6;
  const int lane = tid & 63;

  // locality swizzle over grid (16,134): per-XCD 268-tile run, supertiles 8x16 col-outer
  int lin = blockIdx.x + ((int)blockIdx.y << 4);
  int gt = (lin & 7) * 268 + (lin >> 3);
  int ct, rt, su;
  if (gt < 2048) { su = gt >> 7; int rr = gt & 127; ct = rr >> 3; rt = rr & 7; }
  else           { su = 16;      int rr = gt - 2048; ct = rr / 6; rt = rr % 6; }
  const int by_u = su * 8 + rt;  // 0..133
  const int bx = ct;             // 0..15

  int e, zw, m0l;
  if (by_u < 64) { e = -1; zw = 0; m0l = by_u << 7; }
  else { int q = by_u - 64; e = q / 10; zw = e + 1; m0l = (q % 10) << 7; }
  const long crow0_u = (e < 0) ? (long)m0l : (8192 + (long)e * CAPP + m0l);
  const long n0 = (long)bx * 128;
  const unsigned short* Bm = Wbase + (long)zw * N * K;

  // staging: 4 chunks/thread (2 A + 2 B), pre-swizzled source col
  const int r_ = (w << 4) + (lane >> 2);
  const int p_ = lane & 3;
  const unsigned short* aSrc[2];
  const unsigned short* bSrc[2];
#pragma unroll
  for (int c = 0; c < 2; ++c) {
    int rsg = c * 64 + r_;
    int q = p_ ^ ((rsg >> 1) & 3);
    long arow;
    if (WHICH == 1)
      arow = (e < 0) ? (long)(m0l + rsg) : (long)sel[e * CAPP + m0l + rsg];
    else
      arow = crow0_u + rsg;
    aSrc[c] = Abase + arow * (long)K + q * 8;
    bSrc[c] = Bm + (n0 + rsg) * (long)K + q * 8;
  }
  const int dst0 = tid * 8;

  auto STAGE = [&](int buf, int kt) {
    unsigned short* bufp = lds + buf * 8192;
    const long ko = (long)kt * 32;
#pragma unroll
    for (int c = 0; c < 2; ++c) {
      gload_lds16(aSrc[c] + ko, bufp + c * 2048 + dst0);
      gload_lds16(bSrc[c] + ko, bufp + 4096 + c * 2048 + dst0);
    }
  };

  const int wr = w >> 1, wc = w & 1;
  const int lr = lane & 15, kq = lane >> 4;
  const int slot = (kq ^ ((lr >> 1) & 3)) * 8;
  const int aRow = wr * 64 + lr;
  const int bRow = wc * 64 + lr;

  f32x4 acc[4][4] = {};

  auto COMPUTE = [&](int buf) {
    const unsigned short* aSeg = lds + buf * 8192;
    const unsigned short* bSeg = aSeg + 4096;
    bf16x8 af[4], bf[4];
#pragma unroll
    for (int m = 0; m < 4; ++m)
      af[m] = *(const bf16x8*)&aSeg[(aRow + m * 16) * 32 + slot];
#pragma unroll
    for (int n = 0; n < 4; ++n)
      bf[n] = *(const bf16x8*)&bSeg[(bRow + n * 16) * 32 + slot];
    asm volatile("s_waitcnt lgkmcnt(0)" ::: "memory");
    __builtin_amdgcn_sched_barrier(0);
    __builtin_amdgcn_s_setprio(1);
#pragma unroll
    for (int m = 0; m < 4; ++m)
#pragma unroll
      for (int n = 0; n < 4; ++n)
        acc[m][n] = MFMA16(af[m], bf[n], acc[m][n]);
    __builtin_amdgcn_s_setprio(0);
    __builtin_amdgcn_sched_barrier(0);
  };

  // prologue: stage steps 0,1 into bufs 0,1
  STAGE(0, 0);
  STAGE(1, 1);
  asm volatile("s_waitcnt vmcnt(0)" ::: "memory");
  __builtin_amdgcn_sched_barrier(0);
  __builtin_amdgcn_s_barrier();
  __builtin_amdgcn_sched_barrier(0);

#pragma unroll 1
  for (int i = 0; i < nk2; ++i) {
    if (i + 1 < nk2) {
      STAGE((2 * i + 2) & 3, 2 * i + 2);
      STAGE((2 * i + 3) & 3, 2 * i + 3);
    }
    COMPUTE((2 * i) & 3);
    COMPUTE((2 * i + 1) & 3);
    asm volatile("s_waitcnt vmcnt(0)" ::: "memory");
    __builtin_amdgcn_sched_barrier(0);
    __builtin_amdgcn_s_barrier();
    __builtin_amdgcn_sched_barrier(0);
  }

  // ---- epilogue ----
  const int r0q = (lane >> 4) * 4;
  const int cc = lane & 15;

  if (WHICH == 1) {  // SwiGLU -> a_all bf16 [17152][FD]
    const long gcol0 = (n0 >> 1) + wc * 32;
#pragma unroll
    for (int m = 0; m < 4; ++m)
#pragma unroll
      for (int rj = 0; rj < 4; ++rj) {
        long row = crow0_u + wr * 64 + m * 16 + r0q + rj;
#pragma unroll
        for (int q2 = 0; q2 < 2; ++q2) {
          float x1v = acc[m][2 * q2][rj];
          float x2v = acc[m][2 * q2 + 1][rj];
          float s = x2v / (1.0f + __expf(-x2v));
          obuf[row * FD + gcol0 + q2 * 16 + cc] = f2bf(x1v * s);
        }
      }
  } else {  // unified weighted bf16 -> o_all [17152][2048]
    const long ccol0 = n0 + wc * 64;
#pragma unroll
    for (int m = 0; m < 4; ++m)
#pragma unroll
      for (int rj = 0; rj < 4; ++rj) {
        int lrow = m0l + wr * 64 + m * 16 + r0q + rj;
        float wgt = (e < 0) ? 1.0f : selw[e * CAPP + lrow];
        long row = crow0_u + wr * 64 + m * 16 + r0q + rj;
#pragma unroll
        for (int n = 0; n < 4; ++n)
          obuf[row * DMODEL + ccol0 + n * 16 + cc] = f2bf(acc[m][n][rj] * wgt);
      }
  }
}

extern "C" void kernel_launch(void* const* d_in, const int* in_sizes, int n_in,
                              void* d_out, int out_size, void* d_ws,
                              size_t ws_size, hipStream_t stream) {
  (void)in_sizes; (void)n_in; (void)out_size; (void)ws_size;
  const float* x = (const float*)d_in[0];
  const float* gw = (const float*)d_in[1];
  const float* eb = (const float*)d_in[2];
  const float* sw1 = (const float*)d_in[3];
  const float* sw2 = (const float*)d_in[4];
  const float* rw1 = (const float*)d_in[5];
  const float* rw2 = (const float*)d_in[6];
  float* out = (float*)d_out;

  char* ws = (char*)d_ws;
  size_t off = 0;
  auto alloc = [&](size_t bytes) {
    size_t o = off;
    off += (bytes + 255) & ~(size_t)255;
    return o;
  };
  unsigned short* xb    = (unsigned short*)(ws + alloc((size_t)TOKS * DMODEL * 2));
  unsigned short* w1t   = (unsigned short*)(ws + alloc((size_t)8 * DMODEL * (2 * FD) * 2));
  unsigned short* w2t   = (unsigned short*)(ws + alloc((size_t)8 * DMODEL * FD * 2));
  unsigned short* a_all = (unsigned short*)(ws + alloc((size_t)(TOKS + NEXP * CAPP) * FD * 2));
  unsigned short* o_all = (unsigned short*)(ws + alloc((size_t)(TOKS + NEXP * CAPP) * DMODEL * 2));
  u64* keys = (u64*)(ws + alloc((size_t)NEXP * TOKS * 8));
  int* sel  = (int*)(ws + alloc((size_t)NEXP * CAPP * 4));
  float* selw = (float*)(ws + alloc((size_t)NEXP * CAPP * 4));
  unsigned* cnt = (unsigned*)(ws + alloc((size_t)TOKS * 4));
  int* inv = (int*)(ws + alloc((size_t)TOKS * 2 * 4));

  const size_t LDS4 = 65536;  // 4 x 16 KB rotation buffers

  // 1. fused convert + gating (also zeroes cnt)
  k_conv_gate<<<TOKS, 256, 0, stream>>>(x, gw, eb, xb, keys, cnt);
  // 2./3. vectorized weight transposes (w1 with x1/x2 16-block interleave)
  k_tr64<true><<<dim3(32, 32, 8), 256, 0, stream>>>(sw1, rw1, w1t, DMODEL, 2 * FD);
  k_tr64<false><<<dim3(32, 16, 8), 256, 0, stream>>>(sw2, rw2, w2t, FD, DMODEL);
  // 4. per-expert selection + inverse map
  k_select<<<NEXP, 1024, 0, stream>>>(keys, sel, selw, cnt, inv);
  // 5. GEMM1 (128^2, 2 K-steps/barrier) + SwiGLU -> a_all
  k_ffn<1><<<dim3(16, URT128), 256, LDS4, stream>>>(xb, w1t, a_all, sel, nullptr);
  // 6. GEMM2 (same structure) -> o_all bf16 (shared w=1, routed w=selw)
  k_ffn<2><<<dim3(16, URT128), 256, LDS4, stream>>>(a_all, w2t, o_all, nullptr, selw);
  // 7. combine -> out fp32 (full overwrite)
  k_combine<<<TOKS, 256, 0, stream>>>(out, o_all, inv, cnt);
}